// Round 1
// 1133.846 us; speedup vs baseline: 1.1081x; 1.1081x over previous
//
#include <hip/hip_runtime.h>

#define LN_EPS 1e-5f

typedef __bf16 bf16x8 __attribute__((ext_vector_type(8)));
typedef unsigned short ushort8v __attribute__((ext_vector_type(8)));
typedef float f32x4 __attribute__((ext_vector_type(4)));

__device__ __forceinline__ float bf16_to_f(unsigned short u) {
    unsigned int x = ((unsigned int)u) << 16;
    return __builtin_bit_cast(float, x);
}
__device__ __forceinline__ unsigned short f_to_bf16(float f) {
    unsigned int u = __builtin_bit_cast(unsigned int, f);
    u += 0x7FFFu + ((u >> 16) & 1u);   // round-to-nearest-even
    return (unsigned short)(u >> 16);
}
__device__ __forceinline__ int idx_at(const int* base, int i, int is64) {
    return is64 ? base[(long long)i << 1] : base[i];   // int64 LE: low word holds value
}

// dtype-polymorphic accessors ------------------------------------------------
template<int BF16>
__device__ __forceinline__ bf16x8 load_frag(const void* base, size_t off) {
    if (BF16) {
        return *(const bf16x8*)((const unsigned short*)base + off);
    } else {
        const float* p = (const float*)base + off;
        f32x4 a = *(const f32x4*)p;
        f32x4 b = *(const f32x4*)(p + 4);
        ushort8v u;
        u[0] = f_to_bf16(a[0]); u[1] = f_to_bf16(a[1]);
        u[2] = f_to_bf16(a[2]); u[3] = f_to_bf16(a[3]);
        u[4] = f_to_bf16(b[0]); u[5] = f_to_bf16(b[1]);
        u[6] = f_to_bf16(b[2]); u[7] = f_to_bf16(b[3]);
        return __builtin_bit_cast(bf16x8, u);
    }
}
template<int BF16>
__device__ __forceinline__ float load_sc(const void* base, size_t i) {
    return BF16 ? bf16_to_f(((const unsigned short*)base)[i]) : ((const float*)base)[i];
}
template<int BF16>
__device__ __forceinline__ void store_out(void* out, size_t i, float v) {
    if (BF16) ((unsigned short*)out)[i] = f_to_bf16(v);
    else      ((float*)out)[i] = v;
}

// ---------------------------------------------------------------------------
// flags[0] = edge_index is int64 (1) or int32 (0)
// flags[1] = float buffers are bf16 (1) or fp32 (0)
// ---------------------------------------------------------------------------
__global__ void detect_kernel(const unsigned short* __restrict__ xu,
                              const unsigned int* __restrict__ ei,
                              int N, int* __restrict__ flags)
{
    if (threadIdx.x != 0 || blockIdx.x != 0) return;
    int inrange = 0;
    for (int i = 0; i < 64; ++i) {
        unsigned short u = xu[2 * i];
        int e = (u >> 7) & 0xFF;
        if (e >= 0x60 && e <= 0x8A) inrange++;
    }
    int isbf16 = (inrange >= 48) ? 1 : 0;

    int is64 = 1;
    for (int i = 0; i < 64; ++i) {
        unsigned int lo = ei[2 * i], hi = ei[2 * i + 1];
        if (hi != 0u || lo >= (unsigned int)N) { is64 = 0; break; }
    }
    flags[0] = is64;
    flags[1] = isbf16;
}

// ---------------------------------------------------------------------------
__global__ __launch_bounds__(256) void zero_kernel(float* __restrict__ p, int n4)
{
    int i = blockIdx.x * 256 + threadIdx.x;
    if (i < n4) {
        f32x4 z = {0.f, 0.f, 0.f, 0.f};
        ((f32x4*)p)[i] = z;
    }
}

// ---------------------------------------------------------------------------
// Counting sort of edges by dst: histogram -> exclusive scan -> rank scatter.
// ---------------------------------------------------------------------------
__global__ __launch_bounds__(256) void hist_kernel(
    const int* __restrict__ eidx, int* __restrict__ ecnt,
    const int* __restrict__ flags, int E)
{
    int e = blockIdx.x * 256 + threadIdx.x;
    if (e >= E) return;
    const int is64 = flags[0];
    const int* dstp = eidx + (is64 ? 2 * E : E);
    atomicAdd(&ecnt[idx_at(dstp, e, is64)], 1);
}

// single-block exclusive scan over N counts -> cursor (start offsets)
__global__ __launch_bounds__(1024) void scan_kernel(
    const int* __restrict__ ecnt, int* __restrict__ cursor, int N)
{
    __shared__ int sums[1024];
    const int t = threadIdx.x;
    const int chunk = (N + 1023) >> 10;
    const int s0 = t * chunk;
    const int s1 = (s0 + chunk < N) ? s0 + chunk : N;
    int sum = 0;
    for (int i = s0; i < s1; ++i) sum += ecnt[i];
    sums[t] = sum;
    __syncthreads();
    for (int ofs = 1; ofs < 1024; ofs <<= 1) {
        int v = sums[t];
        int add = (t >= ofs) ? sums[t - ofs] : 0;
        __syncthreads();
        sums[t] = v + add;
        __syncthreads();
    }
    int run = (t == 0) ? 0 : sums[t - 1];
    for (int i = s0; i < s1; ++i) { cursor[i] = run; run += ecnt[i]; }
}

__global__ __launch_bounds__(256) void scatter_kernel(
    const int* __restrict__ eidx, int* __restrict__ cursor,
    int* __restrict__ sorted_e, const int* __restrict__ flags, int E)
{
    int e = blockIdx.x * 256 + threadIdx.x;
    if (e >= E) return;
    const int is64 = flags[0];
    const int* dstp = eidx + (is64 ? 2 * E : E);
    int d = idx_at(dstp, e, is64);
    int pos = atomicAdd(&cursor[d], 1);
    sorted_e[pos] = e;
}

// ---------------------------------------------------------------------------
// W (256x128 k-major) -> bf16 W^T (128x256 n-major) for contiguous B-fragments
// ---------------------------------------------------------------------------
template<int BF16>
__global__ __launch_bounds__(256) void prep_transpose(
    const void* __restrict__ Wm, const void* __restrict__ Wu,
    unsigned short* __restrict__ WmT, unsigned short* __restrict__ WuT,
    const int* __restrict__ flags)
{
    if (flags[1] != BF16) return;
    int idx = blockIdx.x * 256 + threadIdx.x;   // 0 .. 32767
    int k = idx >> 7;
    int n = idx & 127;
    unsigned short wm, wu;
    if (BF16) {
        wm = ((const unsigned short*)Wm)[idx];
        wu = ((const unsigned short*)Wu)[idx];
    } else {
        wm = f_to_bf16(((const float*)Wm)[idx]);
        wu = f_to_bf16(((const float*)Wu)[idx]);
    }
    WmT[n * 256 + k] = wm;
    WuT[n * 256 + k] = wu;
}

// ---------------------------------------------------------------------------
// Edge kernel (dst-sorted): 128 sorted edges / block, 4 waves.
// msg = relu([x[src]|edge_attr] @ W_msg + b_msg); segmented reduction over
// the sorted-by-dst order: interior segments -> plain store, block-boundary
// segments -> atomicAdd. LDS strip double-buffered, 132-float pitch.
// ---------------------------------------------------------------------------
template<int BF16>
__global__ __launch_bounds__(256) void edge_kernel(
    const void* __restrict__ x, const int* __restrict__ eidx,
    const void* __restrict__ ea, const unsigned short* __restrict__ WmT,
    const void* __restrict__ b_msg,
    float* __restrict__ sumbuf, const int* __restrict__ sorted_e,
    const int* __restrict__ flags, int E)
{
    if (flags[1] != BF16) return;
    const int is64 = flags[0];
    const int* srcp = eidx;
    const int* dstp = eidx + (is64 ? 2 * E : E);

    __shared__ int   eS[128];
    __shared__ int   dS[128];
    __shared__ float strip[2][16][132];

    const int pbase = blockIdx.x * 128;
    const int tid  = threadIdx.x;
    const int w    = tid >> 6;
    const int l    = tid & 63;
    const int m    = l & 15;
    const int quad = l >> 4;
    int valid = E - pbase; if (valid > 128) valid = 128;

    if (tid < 128) {
        int p = pbase + tid;
        int pc = p < E ? p : E - 1;
        int e = sorted_e[pc];
        eS[tid] = e;
        dS[tid] = idx_at(dstp, e, is64);
    }

    bf16x8 bfrag[2][8];
#pragma unroll
    for (int nt = 0; nt < 2; ++nt) {
        const unsigned short* p = WmT + (w * 32 + nt * 16 + m) * 256 + quad * 8;
#pragma unroll
        for (int kk = 0; kk < 8; ++kk)
            bfrag[nt][kk] = *(const bf16x8*)(p + kk * 32);
    }
    const float bias0 = load_sc<BF16>(b_msg, w * 32 + m);
    const float bias1 = load_sc<BF16>(b_msg, w * 32 + 16 + m);

    __syncthreads();

    // per-column carry state for the segmented reduction (tid < 128 only)
    int   cur_d   = -1;
    float cur_sum = 0.f;
    int   first   = 1;

    for (int mt = 0; mt < 8; ++mt) {
        const int b = mt & 1;
        const int e_a = eS[mt * 16 + m];
        const int sa  = idx_at(srcp, e_a, is64);
        const size_t xoff = (size_t)sa  * 128 + quad * 8;
        const size_t eoff = (size_t)e_a * 128 + quad * 8;

        f32x4 acc0 = {0.f, 0.f, 0.f, 0.f};
        f32x4 acc1 = {0.f, 0.f, 0.f, 0.f};
#pragma unroll
        for (int kk = 0; kk < 4; ++kk) {
            bf16x8 af = load_frag<BF16>(x, xoff + kk * 32);
            acc0 = __builtin_amdgcn_mfma_f32_16x16x32_bf16(af, bfrag[0][kk], acc0, 0, 0, 0);
            acc1 = __builtin_amdgcn_mfma_f32_16x16x32_bf16(af, bfrag[1][kk], acc1, 0, 0, 0);
        }
#pragma unroll
        for (int kk = 0; kk < 4; ++kk) {
            bf16x8 af = load_frag<BF16>(ea, eoff + kk * 32);
            acc0 = __builtin_amdgcn_mfma_f32_16x16x32_bf16(af, bfrag[0][kk + 4], acc0, 0, 0, 0);
            acc1 = __builtin_amdgcn_mfma_f32_16x16x32_bf16(af, bfrag[1][kk + 4], acc1, 0, 0, 0);
        }

#pragma unroll
        for (int i = 0; i < 4; ++i) {
            float v0 = acc0[i] + bias0; v0 = v0 > 0.f ? v0 : 0.f;
            float v1 = acc1[i] + bias1; v1 = v1 > 0.f ? v1 : 0.f;
            strip[b][quad * 4 + i][w * 32 + m]      = v0;
            strip[b][quad * 4 + i][w * 32 + 16 + m] = v1;
        }
        __syncthreads();

        if (tid < 128) {
            int rmax = valid - mt * 16; if (rmax > 16) rmax = 16;
            for (int r = 0; r < rmax; ++r) {
                int   d = dS[mt * 16 + r];
                float v = strip[b][r][tid];
                if (d == cur_d) {
                    cur_sum += v;
                } else {
                    if (cur_d >= 0) {
                        float* p = &sumbuf[(size_t)cur_d * 128 + tid];
                        if (first) { atomicAdd(p, cur_sum); first = 0; }
                        else       { *p = cur_sum; }
                    }
                    cur_d = d; cur_sum = v;
                }
            }
        }
    }
    if (tid < 128 && cur_d >= 0)
        atomicAdd(&sumbuf[(size_t)cur_d * 128 + tid], cur_sum);   // may span blocks
}

// ---------------------------------------------------------------------------
// Node kernel: 64 nodes / block, 4 waves; wave w owns cols [w*32, w*32+32).
// h = [x | mean_msg] @ W_upd + b_upd; LayerNorm; out = relu(h_ln + x).
// ---------------------------------------------------------------------------
template<int BF16>
__global__ __launch_bounds__(256) void node_kernel(
    const void* __restrict__ x,
    const float* __restrict__ sumbuf, const int* __restrict__ counts,
    const unsigned short* __restrict__ WuT, const void* __restrict__ b_upd,
    const void* __restrict__ gamma_, const void* __restrict__ beta_,
    void* __restrict__ out, const int* __restrict__ flags, int N)
{
    if (flags[1] != BF16) return;

    __shared__ float redS[4][64];
    __shared__ float redQ[4][64];
    __shared__ float muS[64];
    __shared__ float rsS[64];

    const int rbase = blockIdx.x * 64;
    const int tid  = threadIdx.x;
    const int w    = tid >> 6;
    const int l    = tid & 63;
    const int m    = l & 15;
    const int quad = l >> 4;

    bf16x8 bfrag[2][8];
#pragma unroll
    for (int nt = 0; nt < 2; ++nt) {
        const unsigned short* p = WuT + (w * 32 + nt * 16 + m) * 256 + quad * 8;
#pragma unroll
        for (int kk = 0; kk < 8; ++kk)
            bfrag[nt][kk] = *(const bf16x8*)(p + kk * 32);
    }
    const float bias0 = load_sc<BF16>(b_upd, w * 32 + m);
    const float bias1 = load_sc<BF16>(b_upd, w * 32 + 16 + m);

    f32x4 acc[4][2];

    for (int mt = 0; mt < 4; ++mt) {
        int r = rbase + mt * 16 + m;
        int rc = r < N ? r : N - 1;
        const size_t xoff = (size_t)rc * 128 + quad * 8;
        const float* srow = sumbuf + (size_t)rc * 128 + quad * 8;
        const float rcp = 1.0f / fmaxf((float)counts[rc], 1.0f);

        f32x4 a0 = {0.f, 0.f, 0.f, 0.f};
        f32x4 a1 = {0.f, 0.f, 0.f, 0.f};
#pragma unroll
        for (int kk = 0; kk < 4; ++kk) {
            bf16x8 af = load_frag<BF16>(x, xoff + kk * 32);
            a0 = __builtin_amdgcn_mfma_f32_16x16x32_bf16(af, bfrag[0][kk], a0, 0, 0, 0);
            a1 = __builtin_amdgcn_mfma_f32_16x16x32_bf16(af, bfrag[1][kk], a1, 0, 0, 0);
        }
#pragma unroll
        for (int kk = 0; kk < 4; ++kk) {
            const float* sp = srow + kk * 32;
            ushort8v uu;
#pragma unroll
            for (int j = 0; j < 8; ++j) uu[j] = f_to_bf16(sp[j] * rcp);
            bf16x8 av = __builtin_bit_cast(bf16x8, uu);
            a0 = __builtin_amdgcn_mfma_f32_16x16x32_bf16(av, bfrag[0][kk + 4], a0, 0, 0, 0);
            a1 = __builtin_amdgcn_mfma_f32_16x16x32_bf16(av, bfrag[1][kk + 4], a1, 0, 0, 0);
        }

        float ps[4], qs[4];
#pragma unroll
        for (int i = 0; i < 4; ++i) {
            a0[i] += bias0;
            a1[i] += bias1;
            ps[i] = a0[i] + a1[i];
            qs[i] = a0[i] * a0[i] + a1[i] * a1[i];
        }
        acc[mt][0] = a0;
        acc[mt][1] = a1;

#pragma unroll
        for (int s = 1; s < 16; s <<= 1) {
#pragma unroll
            for (int i = 0; i < 4; ++i) {
                ps[i] += __shfl_xor(ps[i], s, 64);
                qs[i] += __shfl_xor(qs[i], s, 64);
            }
        }
        if (m == 0) {
#pragma unroll
            for (int i = 0; i < 4; ++i) {
                redS[w][mt * 16 + quad * 4 + i] = ps[i];
                redQ[w][mt * 16 + quad * 4 + i] = qs[i];
            }
        }
    }
    __syncthreads();

    if (tid < 64) {
        float s = redS[0][tid] + redS[1][tid] + redS[2][tid] + redS[3][tid];
        float q = redQ[0][tid] + redQ[1][tid] + redQ[2][tid] + redQ[3][tid];
        float mu = s * (1.0f / 128.0f);
        float var = q * (1.0f / 128.0f) - mu * mu;
        muS[tid] = mu;
        rsS[tid] = rsqrtf(var + LN_EPS);
    }
    __syncthreads();

    const float g0  = load_sc<BF16>(gamma_, w * 32 + m);
    const float be0 = load_sc<BF16>(beta_,  w * 32 + m);
    const float g1  = load_sc<BF16>(gamma_, w * 32 + 16 + m);
    const float be1 = load_sc<BF16>(beta_,  w * 32 + 16 + m);

    for (int mt = 0; mt < 4; ++mt) {
#pragma unroll
        for (int i = 0; i < 4; ++i) {
            const int ridx = mt * 16 + quad * 4 + i;
            const int r = rbase + ridx;
            if (r < N) {
                const float mu = muS[ridx];
                const float rs = rsS[ridx];
                const size_t c0 = (size_t)r * 128 + w * 32 + m;
                const size_t c1 = c0 + 16;
                float v0 = (acc[mt][0][i] - mu) * rs * g0 + be0 + load_sc<BF16>(x, c0);
                float v1 = (acc[mt][1][i] - mu) * rs * g1 + be1 + load_sc<BF16>(x, c1);
                store_out<BF16>(out, c0, v0 > 0.f ? v0 : 0.f);
                store_out<BF16>(out, c1, v1 > 0.f ? v1 : 0.f);
            }
        }
    }
}

// ---------------------------------------------------------------------------
extern "C" void kernel_launch(void* const* d_in, const int* in_sizes, int n_in,
                              void* d_out, int out_size, void* d_ws, size_t ws_size,
                              hipStream_t stream)
{
    const void* x  = d_in[0];
    const int*  ei = (const int*)d_in[1];
    const void* ea = d_in[2];
    const void* Wm = d_in[3];
    const void* bm = d_in[4];
    const void* Wu = d_in[5];
    const void* bu = d_in[6];
    const void* gm = d_in[7];
    const void* bt = d_in[8];

    const int N = in_sizes[0] / 128;
    const int E = in_sizes[2] / 128;

    // ws layout: flags[4] | sumbuf N*128 f32 | ecnt N i32 | cursor N i32 |
    //            sorted_e E i32 | WmT | WuT
    char* ws = (char*)d_ws;
    int*   flags    = (int*)ws;
    float* sumbuf   = (float*)(ws + 16);
    int*   ecnt     = (int*)(ws + 16 + (size_t)N * 512);
    int*   cursor   = ecnt + N;
    int*   sorted_e = cursor + N;
    unsigned short* WmT = (unsigned short*)(sorted_e + E);
    unsigned short* WuT = WmT + 256 * 128;

    detect_kernel<<<1, 64, 0, stream>>>((const unsigned short*)x,
                                        (const unsigned int*)ei, N, flags);

    // zero sumbuf + ecnt (contiguous N*129 words)
    const int n4 = (N * 129 + 3) / 4;
    zero_kernel<<<(n4 + 255) / 256, 256, 0, stream>>>(sumbuf, n4);

    const int eb256 = (E + 255) / 256;
    hist_kernel<<<eb256, 256, 0, stream>>>(ei, ecnt, flags, E);
    scan_kernel<<<1, 1024, 0, stream>>>(ecnt, cursor, N);
    scatter_kernel<<<eb256, 256, 0, stream>>>(ei, cursor, sorted_e, flags, E);

    prep_transpose<0><<<128, 256, 0, stream>>>(Wm, Wu, WmT, WuT, flags);
    prep_transpose<1><<<128, 256, 0, stream>>>(Wm, Wu, WmT, WuT, flags);

    const int eblocks = (E + 127) / 128;
    edge_kernel<0><<<eblocks, 256, 0, stream>>>(x, ei, ea, WmT, bm, sumbuf, sorted_e, flags, E);
    edge_kernel<1><<<eblocks, 256, 0, stream>>>(x, ei, ea, WmT, bm, sumbuf, sorted_e, flags, E);

    const int nblocks = (N + 63) / 64;
    node_kernel<0><<<nblocks, 256, 0, stream>>>(x, sumbuf, ecnt, WuT, bu, gm, bt, d_out, flags, N);
    node_kernel<1><<<nblocks, 256, 0, stream>>>(x, sumbuf, ecnt, WuT, bu, gm, bt, d_out, flags, N);
}

// Round 2
// 943.547 us; speedup vs baseline: 1.3315x; 1.2017x over previous
//
#include <hip/hip_runtime.h>

#define LN_EPS 1e-5f

typedef __bf16 bf16x8 __attribute__((ext_vector_type(8)));
typedef unsigned short ushort8v __attribute__((ext_vector_type(8)));
typedef float f32x4 __attribute__((ext_vector_type(4)));

__device__ __forceinline__ float bf16_to_f(unsigned short u) {
    unsigned int x = ((unsigned int)u) << 16;
    return __builtin_bit_cast(float, x);
}
__device__ __forceinline__ unsigned short f_to_bf16(float f) {
    unsigned int u = __builtin_bit_cast(unsigned int, f);
    u += 0x7FFFu + ((u >> 16) & 1u);   // round-to-nearest-even
    return (unsigned short)(u >> 16);
}
__device__ __forceinline__ int idx_at(const int* base, int i, int is64) {
    return is64 ? base[(long long)i << 1] : base[i];   // int64 LE: low word holds value
}

// dtype-polymorphic accessors ------------------------------------------------
template<int BF16>
__device__ __forceinline__ bf16x8 load_frag(const void* base, size_t off) {
    if (BF16) {
        return *(const bf16x8*)((const unsigned short*)base + off);
    } else {
        const float* p = (const float*)base + off;
        f32x4 a = *(const f32x4*)p;
        f32x4 b = *(const f32x4*)(p + 4);
        ushort8v u;
        u[0] = f_to_bf16(a[0]); u[1] = f_to_bf16(a[1]);
        u[2] = f_to_bf16(a[2]); u[3] = f_to_bf16(a[3]);
        u[4] = f_to_bf16(b[0]); u[5] = f_to_bf16(b[1]);
        u[6] = f_to_bf16(b[2]); u[7] = f_to_bf16(b[3]);
        return __builtin_bit_cast(bf16x8, u);
    }
}
template<int BF16>
__device__ __forceinline__ float load_sc(const void* base, size_t i) {
    return BF16 ? bf16_to_f(((const unsigned short*)base)[i]) : ((const float*)base)[i];
}
template<int BF16>
__device__ __forceinline__ void store_out(void* out, size_t i, float v) {
    if (BF16) ((unsigned short*)out)[i] = f_to_bf16(v);
    else      ((float*)out)[i] = v;
}

// ---------------------------------------------------------------------------
// flags[0] = edge_index is int64 (1) or int32 (0)
// flags[1] = float buffers are bf16 (1) or fp32 (0)
// ---------------------------------------------------------------------------
__global__ void detect_kernel(const unsigned short* __restrict__ xu,
                              const unsigned int* __restrict__ ei,
                              int N, int* __restrict__ flags)
{
    const int t = threadIdx.x;          // 64 threads
    unsigned short u = xu[2 * t];
    int e = (u >> 7) & 0xFF;
    int okb = (e >= 0x60 && e <= 0x8A) ? 1 : 0;
    unsigned long long bb = __ballot(okb);
    unsigned int lo = ei[2 * t], hi = ei[2 * t + 1];
    int ok64 = (hi == 0u && lo < (unsigned int)N) ? 1 : 0;
    unsigned long long b64 = __ballot(ok64);
    if (t == 0) {
        flags[1] = (__popcll(bb) >= 48) ? 1 : 0;
        flags[0] = (b64 == ~0ull) ? 1 : 0;
    }
}

// ---------------------------------------------------------------------------
__global__ __launch_bounds__(256) void zero_kernel(float* __restrict__ p, int n4)
{
    int i = blockIdx.x * 256 + threadIdx.x;
    if (i < n4) {
        f32x4 z = {0.f, 0.f, 0.f, 0.f};
        ((f32x4*)p)[i] = z;
    }
}

// ---------------------------------------------------------------------------
// Counting sort of edges by dst: histogram -> 2-level scan -> rank scatter.
// ---------------------------------------------------------------------------
__global__ __launch_bounds__(256) void hist_kernel(
    const int* __restrict__ eidx, int* __restrict__ ecnt,
    const int* __restrict__ flags, int E)
{
    int e = blockIdx.x * 256 + threadIdx.x;
    if (e >= E) return;
    const int is64 = flags[0];
    const int* dstp = eidx + (is64 ? 2 * E : E);
    atomicAdd(&ecnt[idx_at(dstp, e, is64)], 1);
}

// block b sums ecnt[b*1024 .. b*1024+1023] -> bsum[b]
__global__ __launch_bounds__(256) void scan_partial(
    const int* __restrict__ ecnt, int* __restrict__ bsum, int N)
{
    __shared__ int red[256];
    const int t = threadIdx.x;
    const int base = blockIdx.x * 1024 + t * 4;
    int s = 0;
    if (base + 3 < N) {
        int4 v = *(const int4*)(ecnt + base);
        s = v.x + v.y + v.z + v.w;
    } else {
        for (int j = 0; j < 4; ++j) if (base + j < N) s += ecnt[base + j];
    }
    red[t] = s;
    __syncthreads();
    for (int ofs = 128; ofs > 0; ofs >>= 1) {
        if (t < ofs) red[t] += red[t + ofs];
        __syncthreads();
    }
    if (t == 0) bsum[blockIdx.x] = red[0];
}

// exclusive scan of bsum[nb] -> bbase[nb]   (nb ~ 49, trivial)
__global__ void scan_base(const int* __restrict__ bsum,
                          int* __restrict__ bbase, int nb)
{
    if (threadIdx.x != 0) return;
    int run = 0;
    for (int i = 0; i < nb; ++i) { bbase[i] = run; run += bsum[i]; }
}

// per-block exclusive scan + base -> cursor
__global__ __launch_bounds__(256) void scan_final(
    const int* __restrict__ ecnt, const int* __restrict__ bbase,
    int* __restrict__ cursor, int N)
{
    __shared__ int tsum[256];
    const int t = threadIdx.x;
    const int base = blockIdx.x * 1024 + t * 4;
    int v0 = 0, v1 = 0, v2 = 0, v3 = 0;
    if (base + 3 < N) {
        int4 u = *(const int4*)(ecnt + base);
        v0 = u.x; v1 = u.y; v2 = u.z; v3 = u.w;
    } else {
        if (base + 0 < N) v0 = ecnt[base + 0];
        if (base + 1 < N) v1 = ecnt[base + 1];
        if (base + 2 < N) v2 = ecnt[base + 2];
        if (base + 3 < N) v3 = ecnt[base + 3];
    }
    tsum[t] = v0 + v1 + v2 + v3;
    __syncthreads();
    for (int ofs = 1; ofs < 256; ofs <<= 1) {
        int val = tsum[t];
        int add = (t >= ofs) ? tsum[t - ofs] : 0;
        __syncthreads();
        tsum[t] = val + add;
        __syncthreads();
    }
    int excl = (t == 0 ? 0 : tsum[t - 1]) + bbase[blockIdx.x];
    int c0 = excl, c1 = c0 + v0, c2 = c1 + v1, c3 = c2 + v2;
    if (base + 3 < N) {
        int4 o = {c0, c1, c2, c3};
        *(int4*)(cursor + base) = o;
    } else {
        if (base + 0 < N) cursor[base + 0] = c0;
        if (base + 1 < N) cursor[base + 1] = c1;
        if (base + 2 < N) cursor[base + 2] = c2;
        if (base + 3 < N) cursor[base + 3] = c3;
    }
}

__global__ __launch_bounds__(256) void scatter_kernel(
    const int* __restrict__ eidx, int* __restrict__ cursor,
    int* __restrict__ se, int* __restrict__ ss, int* __restrict__ sd,
    const int* __restrict__ flags, int E)
{
    int e = blockIdx.x * 256 + threadIdx.x;
    if (e >= E) return;
    const int is64 = flags[0];
    const int* srcp = eidx;
    const int* dstp = eidx + (is64 ? 2 * E : E);
    int d = idx_at(dstp, e, is64);
    int s = idx_at(srcp, e, is64);
    int pos = atomicAdd(&cursor[d], 1);
    se[pos] = e;
    ss[pos] = s;
    sd[pos] = d;
}

// ---------------------------------------------------------------------------
// fp32 path only: x -> bf16 scratch (x is reused ~E/N times in the gather)
// ---------------------------------------------------------------------------
__global__ __launch_bounds__(256) void convert_x(
    const float* __restrict__ x, unsigned short* __restrict__ xb,
    int n8, const int* __restrict__ flags)
{
    if (flags[1]) return;      // bf16 input: kernels use the original pointer
    int i = blockIdx.x * 256 + threadIdx.x;
    if (i >= n8) return;
    const float* p = x + (size_t)i * 8;
    f32x4 a = *(const f32x4*)p;
    f32x4 b = *(const f32x4*)(p + 4);
    ushort8v u;
    u[0] = f_to_bf16(a[0]); u[1] = f_to_bf16(a[1]);
    u[2] = f_to_bf16(a[2]); u[3] = f_to_bf16(a[3]);
    u[4] = f_to_bf16(b[0]); u[5] = f_to_bf16(b[1]);
    u[6] = f_to_bf16(b[2]); u[7] = f_to_bf16(b[3]);
    *(ushort8v*)(xb + (size_t)i * 8) = u;
}

// ---------------------------------------------------------------------------
// W (256x128 k-major) -> bf16 W^T (128x256 n-major) for contiguous B-fragments
// ---------------------------------------------------------------------------
template<int BF16>
__global__ __launch_bounds__(256) void prep_transpose(
    const void* __restrict__ Wm, const void* __restrict__ Wu,
    unsigned short* __restrict__ WmT, unsigned short* __restrict__ WuT,
    const int* __restrict__ flags)
{
    if (flags[1] != BF16) return;
    int idx = blockIdx.x * 256 + threadIdx.x;   // 0 .. 32767
    int k = idx >> 7;
    int n = idx & 127;
    unsigned short wm, wu;
    if (BF16) {
        wm = ((const unsigned short*)Wm)[idx];
        wu = ((const unsigned short*)Wu)[idx];
    } else {
        wm = f_to_bf16(((const float*)Wm)[idx]);
        wu = f_to_bf16(((const float*)Wu)[idx]);
    }
    WmT[n * 256 + k] = wm;
    WuT[n * 256 + k] = wu;
}

// ---------------------------------------------------------------------------
// Edge kernel (dst-sorted): 128 sorted edges / block, 4 waves.
// Phase 1 (barrier-free): msg = relu([x[src]|edge_attr] @ W_msg + b_msg) for
// all 128 edges -> msgbuf LDS (128x130 f32).
// Phase 2 (one barrier): 2-way-parallel segmented reduce over row halves;
// interior segments -> plain store, boundary segments -> atomicAdd.
// ---------------------------------------------------------------------------
template<int BF16>
__global__ __launch_bounds__(256) void edge_kernel(
    const unsigned short* __restrict__ xb,     // bf16 x (xb scratch or orig)
    const void* __restrict__ ea, const unsigned short* __restrict__ WmT,
    const void* __restrict__ b_msg,
    float* __restrict__ sumbuf,
    const int* __restrict__ se, const int* __restrict__ ss,
    const int* __restrict__ sd,
    const int* __restrict__ flags, int E)
{
    if (flags[1] != BF16) return;

    __shared__ float msgbuf[128][130];
    __shared__ int dS[128];

    const int pbase = blockIdx.x * 128;
    const int tid  = threadIdx.x;
    const int w    = tid >> 6;
    const int l    = tid & 63;
    const int m    = l & 15;
    const int quad = l >> 4;
    int valid = E - pbase; if (valid > 128) valid = 128;

    if (tid < 128) {
        int p = pbase + tid;
        dS[tid] = sd[p < E ? p : E - 1];
    }

    // prefetch per-lane edge ids + srcs (independent coalesced loads)
    int my_e[8], my_s[8];
#pragma unroll
    for (int mt = 0; mt < 8; ++mt) {
        int p = pbase + mt * 16 + m;
        if (p >= E) p = E - 1;
        my_e[mt] = se[p];
        my_s[mt] = ss[p];
    }

    bf16x8 bfrag[2][8];
#pragma unroll
    for (int nt = 0; nt < 2; ++nt) {
        const unsigned short* p = WmT + (w * 32 + nt * 16 + m) * 256 + quad * 8;
#pragma unroll
        for (int kk = 0; kk < 8; ++kk)
            bfrag[nt][kk] = *(const bf16x8*)(p + kk * 32);
    }
    const float bias0 = load_sc<BF16>(b_msg, w * 32 + m);
    const float bias1 = load_sc<BF16>(b_msg, w * 32 + 16 + m);

#pragma unroll
    for (int mt = 0; mt < 8; ++mt) {
        const size_t xoff = (size_t)my_s[mt] * 128 + quad * 8;
        const size_t eoff = (size_t)my_e[mt] * 128 + quad * 8;

        f32x4 acc0 = {0.f, 0.f, 0.f, 0.f};
        f32x4 acc1 = {0.f, 0.f, 0.f, 0.f};
#pragma unroll
        for (int kk = 0; kk < 4; ++kk) {
            bf16x8 af = *(const bf16x8*)(xb + xoff + kk * 32);
            acc0 = __builtin_amdgcn_mfma_f32_16x16x32_bf16(af, bfrag[0][kk], acc0, 0, 0, 0);
            acc1 = __builtin_amdgcn_mfma_f32_16x16x32_bf16(af, bfrag[1][kk], acc1, 0, 0, 0);
        }
#pragma unroll
        for (int kk = 0; kk < 4; ++kk) {
            bf16x8 af = load_frag<BF16>(ea, eoff + kk * 32);
            acc0 = __builtin_amdgcn_mfma_f32_16x16x32_bf16(af, bfrag[0][kk + 4], acc0, 0, 0, 0);
            acc1 = __builtin_amdgcn_mfma_f32_16x16x32_bf16(af, bfrag[1][kk + 4], acc1, 0, 0, 0);
        }

#pragma unroll
        for (int i = 0; i < 4; ++i) {
            float v0 = acc0[i] + bias0; v0 = v0 > 0.f ? v0 : 0.f;
            float v1 = acc1[i] + bias1; v1 = v1 > 0.f ? v1 : 0.f;
            const int row = mt * 16 + quad * 4 + i;
            msgbuf[row][w * 32 + m]      = v0;
            msgbuf[row][w * 32 + 16 + m] = v1;
        }
    }
    __syncthreads();

    // phase 2: segmented reduce, rows split in two halves for 2x parallelism
    const int half = tid >> 7;
    const int col  = tid & 127;
    const int r0 = half * 64;
    int r1 = r0 + 64; if (r1 > valid) r1 = valid;
    if (r0 < r1) {
        int   cur_d = dS[r0];
        float s     = msgbuf[r0][col];
        int   first = 1;
        for (int r = r0 + 1; r < r1; ++r) {
            float v = msgbuf[r][col];
            int   d = dS[r];
            if (d == cur_d) {
                s += v;
            } else {
                float* p = &sumbuf[(size_t)cur_d * 128 + col];
                if (first) { atomicAdd(p, s); first = 0; }
                else       { *p = s; }          // interior segment: complete
                cur_d = d; s = v;
            }
        }
        atomicAdd(&sumbuf[(size_t)cur_d * 128 + col], s);  // may span halves/blocks
    }
}

// ---------------------------------------------------------------------------
// Node kernel: 64 nodes / block, 4 waves; wave w owns cols [w*32, w*32+32).
// h = [x | mean_msg] @ W_upd + b_upd; LayerNorm; out = relu(h_ln + x).
// ---------------------------------------------------------------------------
template<int BF16>
__global__ __launch_bounds__(256) void node_kernel(
    const void* __restrict__ x, const unsigned short* __restrict__ xbn,
    const float* __restrict__ sumbuf, const int* __restrict__ counts,
    const unsigned short* __restrict__ WuT, const void* __restrict__ b_upd,
    const void* __restrict__ gamma_, const void* __restrict__ beta_,
    void* __restrict__ out, const int* __restrict__ flags, int N)
{
    if (flags[1] != BF16) return;

    __shared__ float redS[4][64];
    __shared__ float redQ[4][64];
    __shared__ float muS[64];
    __shared__ float rsS[64];

    const int rbase = blockIdx.x * 64;
    const int tid  = threadIdx.x;
    const int w    = tid >> 6;
    const int l    = tid & 63;
    const int m    = l & 15;
    const int quad = l >> 4;

    bf16x8 bfrag[2][8];
#pragma unroll
    for (int nt = 0; nt < 2; ++nt) {
        const unsigned short* p = WuT + (w * 32 + nt * 16 + m) * 256 + quad * 8;
#pragma unroll
        for (int kk = 0; kk < 8; ++kk)
            bfrag[nt][kk] = *(const bf16x8*)(p + kk * 32);
    }
    const float bias0 = load_sc<BF16>(b_upd, w * 32 + m);
    const float bias1 = load_sc<BF16>(b_upd, w * 32 + 16 + m);

    f32x4 acc[4][2];

    for (int mt = 0; mt < 4; ++mt) {
        int r = rbase + mt * 16 + m;
        int rc = r < N ? r : N - 1;
        const size_t xoff = (size_t)rc * 128 + quad * 8;
        const float* srow = sumbuf + (size_t)rc * 128 + quad * 8;
        const float rcp = 1.0f / fmaxf((float)counts[rc], 1.0f);

        f32x4 a0 = {0.f, 0.f, 0.f, 0.f};
        f32x4 a1 = {0.f, 0.f, 0.f, 0.f};
#pragma unroll
        for (int kk = 0; kk < 4; ++kk) {
            bf16x8 af = *(const bf16x8*)(xbn + xoff + kk * 32);
            a0 = __builtin_amdgcn_mfma_f32_16x16x32_bf16(af, bfrag[0][kk], a0, 0, 0, 0);
            a1 = __builtin_amdgcn_mfma_f32_16x16x32_bf16(af, bfrag[1][kk], a1, 0, 0, 0);
        }
#pragma unroll
        for (int kk = 0; kk < 4; ++kk) {
            const float* sp = srow + kk * 32;
            ushort8v uu;
#pragma unroll
            for (int j = 0; j < 8; ++j) uu[j] = f_to_bf16(sp[j] * rcp);
            bf16x8 av = __builtin_bit_cast(bf16x8, uu);
            a0 = __builtin_amdgcn_mfma_f32_16x16x32_bf16(av, bfrag[0][kk + 4], a0, 0, 0, 0);
            a1 = __builtin_amdgcn_mfma_f32_16x16x32_bf16(av, bfrag[1][kk + 4], a1, 0, 0, 0);
        }

        float ps[4], qs[4];
#pragma unroll
        for (int i = 0; i < 4; ++i) {
            a0[i] += bias0;
            a1[i] += bias1;
            ps[i] = a0[i] + a1[i];
            qs[i] = a0[i] * a0[i] + a1[i] * a1[i];
        }
        acc[mt][0] = a0;
        acc[mt][1] = a1;

#pragma unroll
        for (int s = 1; s < 16; s <<= 1) {
#pragma unroll
            for (int i = 0; i < 4; ++i) {
                ps[i] += __shfl_xor(ps[i], s, 64);
                qs[i] += __shfl_xor(qs[i], s, 64);
            }
        }
        if (m == 0) {
#pragma unroll
            for (int i = 0; i < 4; ++i) {
                redS[w][mt * 16 + quad * 4 + i] = ps[i];
                redQ[w][mt * 16 + quad * 4 + i] = qs[i];
            }
        }
    }
    __syncthreads();

    if (tid < 64) {
        float s = redS[0][tid] + redS[1][tid] + redS[2][tid] + redS[3][tid];
        float q = redQ[0][tid] + redQ[1][tid] + redQ[2][tid] + redQ[3][tid];
        float mu = s * (1.0f / 128.0f);
        float var = q * (1.0f / 128.0f) - mu * mu;
        muS[tid] = mu;
        rsS[tid] = rsqrtf(var + LN_EPS);
    }
    __syncthreads();

    const float g0  = load_sc<BF16>(gamma_, w * 32 + m);
    const float be0 = load_sc<BF16>(beta_,  w * 32 + m);
    const float g1  = load_sc<BF16>(gamma_, w * 32 + 16 + m);
    const float be1 = load_sc<BF16>(beta_,  w * 32 + 16 + m);

    for (int mt = 0; mt < 4; ++mt) {
#pragma unroll
        for (int i = 0; i < 4; ++i) {
            const int ridx = mt * 16 + quad * 4 + i;
            const int r = rbase + ridx;
            if (r < N) {
                const float mu = muS[ridx];
                const float rs = rsS[ridx];
                const size_t c0 = (size_t)r * 128 + w * 32 + m;
                const size_t c1 = c0 + 16;
                float v0 = (acc[mt][0][i] - mu) * rs * g0 + be0 + load_sc<BF16>(x, c0);
                float v1 = (acc[mt][1][i] - mu) * rs * g1 + be1 + load_sc<BF16>(x, c1);
                store_out<BF16>(out, c0, v0 > 0.f ? v0 : 0.f);
                store_out<BF16>(out, c1, v1 > 0.f ? v1 : 0.f);
            }
        }
    }
}

// ---------------------------------------------------------------------------
extern "C" void kernel_launch(void* const* d_in, const int* in_sizes, int n_in,
                              void* d_out, int out_size, void* d_ws, size_t ws_size,
                              hipStream_t stream)
{
    const void* x  = d_in[0];
    const int*  ei = (const int*)d_in[1];
    const void* ea = d_in[2];
    const void* Wm = d_in[3];
    const void* bm = d_in[4];
    const void* Wu = d_in[5];
    const void* bu = d_in[6];
    const void* gm = d_in[7];
    const void* bt = d_in[8];

    const int N = in_sizes[0] / 128;
    const int E = in_sizes[2] / 128;

    // ws layout: flags[4] | sumbuf N*128 f32 | ecnt N i32 | cursor N i32 |
    //            bsum 256 | bbase 256 | se E | ss E | sd E | xb N*128 bf16 |
    //            WmT | WuT
    char* ws = (char*)d_ws;
    int*   flags    = (int*)ws;
    float* sumbuf   = (float*)(ws + 16);
    int*   ecnt     = (int*)(ws + 16 + (size_t)N * 512);
    int*   cursor   = ecnt + N;
    int*   bsum     = cursor + N;
    int*   bbase    = bsum + 256;
    int*   se       = bbase + 256;
    int*   ss       = se + E;
    int*   sd       = ss + E;
    unsigned short* xb  = (unsigned short*)(sd + E);
    unsigned short* WmT = xb + (size_t)N * 128;
    unsigned short* WuT = WmT + 256 * 128;

    detect_kernel<<<1, 64, 0, stream>>>((const unsigned short*)x,
                                        (const unsigned int*)ei, N, flags);

    // zero sumbuf + ecnt (contiguous N*129 words)
    const int n4 = (N * 129 + 3) / 4;
    zero_kernel<<<(n4 + 255) / 256, 256, 0, stream>>>(sumbuf, n4);

    const int eb256 = (E + 255) / 256;
    hist_kernel<<<eb256, 256, 0, stream>>>(ei, ecnt, flags, E);

    const int nb = (N + 1023) / 1024;
    scan_partial<<<nb, 256, 0, stream>>>(ecnt, bsum, N);
    scan_base<<<1, 64, 0, stream>>>(bsum, bbase, nb);
    scan_final<<<nb, 256, 0, stream>>>(ecnt, bbase, cursor, N);

    scatter_kernel<<<eb256, 256, 0, stream>>>(ei, cursor, se, ss, sd, flags, E);

    const int n8 = N * 16;
    convert_x<<<(n8 + 255) / 256, 256, 0, stream>>>((const float*)x, xb, n8, flags);

    prep_transpose<0><<<128, 256, 0, stream>>>(Wm, Wu, WmT, WuT, flags);
    prep_transpose<1><<<128, 256, 0, stream>>>(Wm, Wu, WmT, WuT, flags);

    const int eblocks = (E + 127) / 128;
    edge_kernel<0><<<eblocks, 256, 0, stream>>>(xb, ea, WmT, bm, sumbuf, se, ss, sd, flags, E);
    edge_kernel<1><<<eblocks, 256, 0, stream>>>((const unsigned short*)x, ea, WmT, bm,
                                                sumbuf, se, ss, sd, flags, E);

    const int nblocks = (N + 63) / 64;
    node_kernel<0><<<nblocks, 256, 0, stream>>>(x, xb, sumbuf, ecnt, WuT, bu, gm, bt, d_out, flags, N);
    node_kernel<1><<<nblocks, 256, 0, stream>>>(x, (const unsigned short*)x, sumbuf, ecnt,
                                                WuT, bu, gm, bt, d_out, flags, N);
}